// Round 1
// baseline (154.104 us; speedup 1.0000x reference)
//
#include <hip/hip_runtime.h>

typedef __attribute__((ext_vector_type(8))) short bf16x8;
typedef __attribute__((ext_vector_type(4))) short bf16x4;
typedef __attribute__((ext_vector_type(4))) float f32x4;

#if __has_builtin(__builtin_amdgcn_exp2f)
#define EXP2(x) __builtin_amdgcn_exp2f(x)
#else
#define EXP2(x) exp2f(x)
#endif

__device__ __forceinline__ unsigned short f2bf(float f) {
    union { float f; unsigned int u; } v; v.f = f;
    unsigned int r = v.u + 0x7fffu + ((v.u >> 16) & 1u);
    return (unsigned short)(r >> 16);
}

__device__ __forceinline__ float asf(unsigned int u) {
    union { unsigned int u; float f; } v; v.u = u; return v.f;
}

// sqrt( (1/sqrt(32)) * log2(e) ) — baked into BOTH xqT operands so QK^T
// emerges pre-multiplied by scale*log2e: exp2(raw score) == softmax numerator.
#define QK_PRESCALE 0.50500983f

// ---------------------------------------------------------------------------
// Kernel 1: grouped 1x1 conv, 1024 blocks (was 256 -> 1 block/CU).
// block = 64 n-positions x 4 i-groups (one wave per i-group of 8 channels).
// Writes xqT [h][n][i] (bf16, i contiguous, PRE-SCALED)  -> QK MFMA operands
//        xv  [h][i][n] (bf16, n contiguous)              -> PV A-op (V=elu(x))
// ---------------------------------------------------------------------------
__global__ __launch_bounds__(256) void conv_kernel(
    const float* __restrict__ points, const float* __restrict__ conv_w,
    const float* __restrict__ conv_b,
    unsigned short* __restrict__ xqT, unsigned short* __restrict__ xv)
{
    __shared__ float w[1024];
    const int h  = blockIdx.x >> 6;   // 16 heads
    const int nc = blockIdx.x & 63;   // 64 n-chunks of 64
    const int g  = h & 7;
    const int tid = threadIdx.x;
    const float* wg = conv_w + g * 1024;
    for (int k = tid; k < 1024; k += 256) w[k] = wg[k];
    __syncthreads();
    const int n  = nc * 64 + (tid & 63);
    const int ig = tid >> 6;          // wave id -> channels [ig*8, ig*8+8)
    const float* p = points + (size_t)h * 32 * 4096 + n;
    float pv[32];
#pragma unroll
    for (int j = 0; j < 32; ++j) pv[j] = p[(size_t)j * 4096];
    float out[8];
#pragma unroll
    for (int ii = 0; ii < 8; ++ii) {
        const int i = ig * 8 + ii;
        float acc = conv_b[g * 32 + i];
        const float4* w4 = (const float4*)(w + i * 32);   // ds_read_b128
#pragma unroll
        for (int j4 = 0; j4 < 8; ++j4) {
            float4 ww = w4[j4];
            acc += ww.x * pv[j4 * 4]     + ww.y * pv[j4 * 4 + 1]
                 + ww.z * pv[j4 * 4 + 2] + ww.w * pv[j4 * 4 + 3];
        }
        out[ii] = acc;
    }
    unsigned short tq[8];
#pragma unroll
    for (int ii = 0; ii < 8; ++ii) tq[ii] = f2bf(out[ii] * QK_PRESCALE);
    *(bf16x8*)(xqT + ((size_t)h * 4096 + n) * 32 + ig * 8) = *(bf16x8*)tq;
#pragma unroll
    for (int ii = 0; ii < 8; ++ii) {
        float x = out[ii];
        float e = x > 0.f ? x : (__expf(x) - 1.f);   // elu
        xv[((size_t)h * 32 + ig * 8 + ii) * 4096 + n] = f2bf(e);
    }
}

// ---------------------------------------------------------------------------
// Kernel 2: flash attention. R7/R8 skeleton (1024 blocks, 128-key chunks,
// prefetch across the barrier), K fragments direct global->reg double-buffered.
// R9: the P score matrix no longer round-trips through LDS. The only data
// movement P needs is a redistribution among the 4 lanes sharing a query
// column (the quads, lanes +-16/32 apart): producer lane holds keys
// s*16+quad*4+r, the PV B-operand needs keys ng*32+quad*8+j. Bit-mapping
// key=16s1+8s0+4q1+2q0+p => consumer quad=(s0,q1), dword=(q0,p), ng=s1:
// for each dword pair (alpha from s in {0,2}, beta from s in {1,3}) one
// v_permlane32_swap_b32 + one v_permlane16_swap_b32 produces TWO finished
// P-fragment dwords (pure VALU, no LDS, no lgkm wait). Removes 8 w64 + 4
// r128 LDS instrs + their bank conflicts per wave-chunk (~45% of remaining
// LDS-pipe demand, which R8 showed was the top pipe at ~56% incl conflicts)
// and shortens the serial MFMA->exp->LDS->MFMA chain. Frees Pl (9216 B).
// __launch_bounds__(256,4) pins VGPR <= 128 so 4 blocks/CU survives.
// ---------------------------------------------------------------------------
#define VSTR 136   // 128 + 8 pad shorts

#if __has_builtin(__builtin_amdgcn_cvt_pk_bf16_f32)
typedef __attribute__((ext_vector_type(2))) __bf16 bf16x2v;
__device__ __forceinline__ bf16x4 exp_pack(f32x4 sc, float& lsum) {
    float e0 = EXP2(sc[0]), e1 = EXP2(sc[1]);
    float e2 = EXP2(sc[2]), e3 = EXP2(sc[3]);
    lsum += (e0 + e1) + (e2 + e3);
    union { bf16x2v v[2]; bf16x4 s; } u;
    u.v[0] = __builtin_amdgcn_cvt_pk_bf16_f32(e0, e1);
    u.v[1] = __builtin_amdgcn_cvt_pk_bf16_f32(e2, e3);
    return u.s;
}
#else
__device__ __forceinline__ bf16x4 exp_pack(f32x4 sc, float& lsum) {
    union { float f; unsigned int u; } e0, e1, e2, e3;
    e0.f = EXP2(sc[0]); e1.f = EXP2(sc[1]); e2.f = EXP2(sc[2]); e3.f = EXP2(sc[3]);
    unsigned int t0 = e0.u & 0xffff0000u, t1 = e1.u & 0xffff0000u;
    unsigned int t2 = e2.u & 0xffff0000u, t3 = e3.u & 0xffff0000u;
    lsum += (asf(t0) + asf(t1)) + (asf(t2) + asf(t3));
    union { unsigned int d[2]; bf16x4 v; } pk;
    pk.d[0] = (t0 >> 16) | t1;
    pk.d[1] = (t2 >> 16) | t3;
    return pk.v;
}
#endif

// One 128-key chunk: stage V, prefetch next V (regs) + next K frags (KP),
// compute 8 x 16-key steps from current K frags (KU). pf wraps to 0 on the
// last chunk (harmless valid-memory prefetch, no branch).
#define CHUNK(C0, KU, KP)                                                      \
    {                                                                          \
        __syncthreads();                                                       \
        *(bf16x8*)(Vt + vi * VSTR + vn)      = va;                             \
        *(bf16x8*)(Vt + vi * VSTR + vn + 64) = vb;                             \
        __syncthreads();                                                       \
        const int pfb = ((C0) + 128) & 4095;                                   \
        va = *(const bf16x8*)(vbase + (size_t)vi * 4096 + pfb + vn);           \
        vb = *(const bf16x8*)(vbase + (size_t)vi * 4096 + pfb + vn + 64);      \
        _Pragma("unroll")                                                      \
        for (int s8 = 0; s8 < 8; ++s8)                                         \
            KP[s8] = *(const bf16x8*)(kfp + (size_t)(pfb + s8 * 16) * 32);     \
        _Pragma("unroll")                                                      \
        for (int sub = 0; sub < 2; ++sub) {                                    \
            union { bf16x4 v; unsigned int d[2]; } E[4];                       \
            _Pragma("unroll")                                                  \
            for (int s = 0; s < 4; ++s) {                                      \
                f32x4 sc = __builtin_amdgcn_mfma_f32_16x16x32_bf16(            \
                    KU[sub * 4 + s], qfrag, (f32x4){0.f, 0.f, 0.f, 0.f},       \
                    0, 0, 0);                                                  \
                E[s].v = exp_pack(sc, lsum);                                   \
            }                                                                  \
            union { unsigned int d[4]; bf16x8 v; } F0, F1;                     \
            _Pragma("unroll")                                                  \
            for (int p = 0; p < 2; ++p) {                                      \
                unsigned int a0 = E[0].d[p], b0 = E[1].d[p];                   \
                asm("v_permlane32_swap_b32 %0, %1" : "+v"(a0), "+v"(b0));      \
                asm("v_permlane16_swap_b32 %0, %1" : "+v"(a0), "+v"(b0));      \
                F0.d[p] = a0; F0.d[2 + p] = b0;                                \
                unsigned int a1 = E[2].d[p], b1 = E[3].d[p];                   \
                asm("v_permlane32_swap_b32 %0, %1" : "+v"(a1), "+v"(b1));      \
                asm("v_permlane16_swap_b32 %0, %1" : "+v"(a1), "+v"(b1));      \
                F1.d[p] = a1; F1.d[2 + p] = b1;                                \
            }                                                                  \
            _Pragma("unroll")                                                  \
            for (int ng = 0; ng < 2; ++ng) {                                   \
                bf16x8 pfrag = ng ? F1.v : F0.v;                               \
                const int col = sub * 64 + ng * 32 + quad * 8;                 \
                bf16x8 v0 = *(const bf16x8*)(Vt + l15 * VSTR + col);           \
                bf16x8 v1 = *(const bf16x8*)(Vt + (16 + l15) * VSTR + col);    \
                acc0 = __builtin_amdgcn_mfma_f32_16x16x32_bf16(v0, pfrag,      \
                                                               acc0, 0, 0, 0); \
                acc1 = __builtin_amdgcn_mfma_f32_16x16x32_bf16(v1, pfrag,      \
                                                               acc1, 0, 0, 0); \
            }                                                                  \
        }                                                                      \
    }

__global__ __launch_bounds__(256, 4) void attn_kernel(
    const unsigned short* __restrict__ xqT,
    const unsigned short* __restrict__ xv,
    const float* __restrict__ points,
    float* __restrict__ z)
{
    __shared__ unsigned short Vt[32 * VSTR];    // [i][n]    8704 B

    const int h  = blockIdx.y;
    const int b = h >> 3, g = h & 7;
    const int tid = threadIdx.x;
    const int wv = tid >> 6, lane = tid & 63;
    const int quad = lane >> 4, l15 = lane & 15;

    const int m = blockIdx.x * 64 + wv * 16 + l15;   // this lane's query col

    const unsigned short* kbase = xqT + (size_t)h * 4096 * 32;
    const unsigned short* vbase = xv  + (size_t)h * 32 * 4096;

    // Q fragment (B-operand): col=l15, k=quad*8+j
    const bf16x8 qfrag = *(const bf16x8*)(kbase + (size_t)m * 32 + quad * 8);

    f32x4 acc0 = {0.f, 0.f, 0.f, 0.f};   // O rows i = 0..15
    f32x4 acc1 = {0.f, 0.f, 0.f, 0.f};   // O rows i = 16..31
    float lsum = 0.f;

    const int vi = tid >> 3, vn = (tid & 7) * 8;   // V staging: [i][n], 2 cols

    // per-lane K-fragment base: row l15, cols quad*8..+8 (A-operand K^T).
    // For key block n: frag = kfp + n*32.  Wave's 8 frags of a chunk are a
    // permutation of one aligned 1KB block -> fully coalesced dwordx4 loads.
    const unsigned short* kfp = kbase + (size_t)l15 * 32 + quad * 8;

    // V staging prefetch regs (chunk 0)
    const unsigned short* vptr = vbase + (size_t)vi * 4096 + vn;
    bf16x8 va = *(const bf16x8*)vptr;
    bf16x8 vb = *(const bf16x8*)(vptr + 64);

    // K fragment double buffer (chunk 0 into kA)
    bf16x8 kA[8], kB[8];
#pragma unroll
    for (int s8 = 0; s8 < 8; ++s8)
        kA[s8] = *(const bf16x8*)(kfp + (size_t)(s8 * 16) * 32);

    for (int n0 = 0; n0 < 4096; n0 += 256) {
        CHUNK(n0,       kA, kB);
        CHUNK(n0 + 128, kB, kA);
    }

    // denominator: sum partial l over the 4 quads sharing column m
    lsum += __shfl_xor(lsum, 16, 64);
    lsum += __shfl_xor(lsum, 32, 64);
    const float inv = 1.f / lsum;

    const float* pb = points + (size_t)b * 256 * 4096;
    float* zb = z + (size_t)b * 256 * 4096;
#pragma unroll
    for (int half = 0; half < 2; ++half) {
        f32x4 a = half ? acc1 : acc0;
#pragma unroll
        for (int r = 0; r < 4; ++r) {
            int i = half * 16 + quad * 4 + r;             // C/D row mapping
            size_t off = (size_t)(i * 8 + g) * 4096 + m;  // channel shuffle
            zb[off] = a[r] * inv + pb[off];               // + identity
        }
    }
}

// ---------------------------------------------------------------------------
// Kernel 3: GroupNorm partial stats. 256 blocks = 4 per (b, gn_group),
// DISTINCT output slots (no atomics). Each block: 8192 floats (32 KB).
// ---------------------------------------------------------------------------
__global__ __launch_bounds__(256) void gn_stats(const float* __restrict__ z,
                                                float* __restrict__ pstats)
{
    const int blk = blockIdx.x;              // group*4 + quarter
    const int tid = threadIdx.x;
    const float4* p = (const float4*)(z + (size_t)blk * 8192);
    float s = 0.f, ss = 0.f;
    for (int k = tid; k < 2048; k += 256) {
        float4 v = p[k];
        s  += v.x + v.y + v.z + v.w;
        ss += v.x * v.x + v.y * v.y + v.z * v.z + v.w * v.w;
    }
#pragma unroll
    for (int off = 32; off > 0; off >>= 1) {
        s  += __shfl_down(s, off, 64);
        ss += __shfl_down(ss, off, 64);
    }
    __shared__ float red[8];
    const int w = tid >> 6;
    if ((tid & 63) == 0) { red[w * 2] = s; red[w * 2 + 1] = ss; }
    __syncthreads();
    if (tid == 0) {
        s  = red[0] + red[2] + red[4] + red[6];
        ss = red[1] + red[3] + red[5] + red[7];
        pstats[blk * 2]     = s;
        pstats[blk * 2 + 1] = ss;
    }
}

// ---------------------------------------------------------------------------
// Kernel 4: GroupNorm apply, in place on d_out; combines 4 partial sums.
// ---------------------------------------------------------------------------
__global__ __launch_bounds__(256) void gn_apply(float* __restrict__ z,
                                                const float* __restrict__ pstats,
                                                const float* __restrict__ gw,
                                                const float* __restrict__ gb)
{
    const int idx = blockIdx.x * 256 + threadIdx.x;  // float4 index
    float4* p = (float4*)z;
    float4 v = p[idx];
    const int chg = idx >> 10;       // global channel b*256+ch
    const int grp = chg >> 3;        // group slot = b*32 + ch/8
    const int ch  = chg & 255;
    const float4 s4  = *(const float4*)(pstats + grp * 8);      // s0,ss0,s1,ss1
    const float4 s4b = *(const float4*)(pstats + grp * 8 + 4);  // s2,ss2,s3,ss3
    const float s  = s4.x + s4.z + s4b.x + s4b.z;
    const float ss = s4.y + s4.w + s4b.y + s4b.w;
    const float mean = s * (1.f / 32768.f);
    const float var  = ss * (1.f / 32768.f) - mean * mean;
    const float rstd = rsqrtf(var + 1e-5f);
    const float w  = gw[ch] * rstd;
    const float bb = gb[ch] - mean * w;
    v.x = v.x * w + bb; v.y = v.y * w + bb;
    v.z = v.z * w + bb; v.w = v.w * w + bb;
    p[idx] = v;
}

extern "C" void kernel_launch(void* const* d_in, const int* in_sizes, int n_in,
                              void* d_out, int out_size, void* d_ws, size_t ws_size,
                              hipStream_t stream)
{
    const float* points = (const float*)d_in[0];
    const float* conv_w = (const float*)d_in[1];
    const float* conv_b = (const float*)d_in[2];
    const float* gn_w   = (const float*)d_in[3];
    const float* gn_b   = (const float*)d_in[4];
    float* out = (float*)d_out;
    char* ws = (char*)d_ws;
    unsigned short* xqT = (unsigned short*)ws;                             // 4 MB
    unsigned short* xv  = (unsigned short*)(ws + (size_t)4 * 1024 * 1024); // 4 MB
    float* pstats = (float*)(ws + (size_t)8 * 1024 * 1024);                // 2 KB

    conv_kernel<<<1024, 256, 0, stream>>>(points, conv_w, conv_b, xqT, xv);
    attn_kernel<<<dim3(64, 16), 256, 0, stream>>>(xqT, xv, points, out);
    gn_stats<<<256, 256, 0, stream>>>(out, pstats);
    gn_apply<<<2048, 256, 0, stream>>>(out, pstats, gn_w, gn_b);
}